// Round 3
// baseline (131.301 us; speedup 1.0000x reference)
//
#include <hip/hip_runtime.h>
#include <math.h>

#define NA   21
#define NM   64
#define ND   210
#define DP   224            // padded descriptor row
#define NT   8192
#define NCH  28             // 8-wide k-chunks per descriptor row (224/8)
#define KS2  32             // stage2 K-splits (256 t each)

#define QC 0.22360679774997896f   // sqrt(5)/10
#define KE 0.016666666666666666f  // 5/(3*sig^2)

typedef short bf8 __attribute__((ext_vector_type(8)));   // 8 bf16 (4 VGPRs)
typedef float f4  __attribute__((ext_vector_type(4)));   // 4 fp32 acc

// ---- workspace layout (float offsets); bf16 arrays count elems/2 ----
// XfT/JfT: stage2 B frags [dtile 14][tq 1024][col_d 16][8 t]
// w1f/e1f: stage2 A frags [mtile 4][tq 1024][col_m 16][8 t]
// Af     : stage1 A frags [mtile 4][kq 28][col_m 16][8 d]
// AB     : [m 64][d 224] fp32 atomic accumulator (stage2 output)
// EsA/WaA: [m 64] fp32 atomic accumulators (stage1 epilogue)
#define O_XFT  1835008u
#define O_JFT  2752512u
#define O_W1   3670016u
#define O_E1   3932160u
#define O_AF   4194304u
#define O_QG   4201472u        // qxsG fp32 [56][64][4]
#define O_NX   4232192u        // [64]
#define O_AB   4261056u        // [64][224]
#define O_ESA  4275456u        // [64]
#define O_WAA  4275520u        // [64]

__device__ __forceinline__ unsigned short f2bf(float f) {
    unsigned u = __float_as_uint(f);
    u += 0x7fffu + ((u >> 16) & 1u);
    return (unsigned short)(u >> 16);
}
__device__ __forceinline__ float bf2f(unsigned short h) {
    return __uint_as_float((unsigned)h << 16);
}

__device__ __forceinline__ void d_to_ij(int d, int& i, int& j) {
    int ii = (int)((1.0f + sqrtf(1.0f + 8.0f * (float)d)) * 0.5f);
    while (ii * (ii - 1) / 2 > d) --ii;
    while ((ii + 1) * ii / 2 <= d) ++ii;
    i = ii;
    j = d - ii * (ii - 1) / 2;
}

// Tiny geometry prep: per-molecule descriptors -> Af frags, qxsG, nx.
// Also zero-inits the atomic accumulators (AB, EsA, WaA) so downstream
// kernels can accumulate with device atomics (handles workspace re-poison).
__global__ __launch_bounds__(256) void k_geom(
    const float* __restrict__ Rs, unsigned short* __restrict__ Af,
    float* __restrict__ qxsG, float* __restrict__ nx,
    float* __restrict__ AB, float* __restrict__ EsA, float* __restrict__ WaA) {
    const int m = blockIdx.x, tid = threadIdx.x;
    __shared__ float R[NA * 3];
    __shared__ float red[256];
    if (tid < NA * 3) R[tid] = Rs[m * NA * 3 + tid];
    if (tid < DP) AB[m * DP + tid] = 0.0f;
    if (tid == 0) { EsA[m] = 0.0f; WaA[m] = 0.0f; }
    __syncthreads();
    float local = 0.0f;
    if (tid < DP) {
        float vr = 0.0f;
        unsigned short hv = 0;
        if (tid < ND) {
            int i, j; d_to_ij(tid, i, j);
            float dx = R[i * 3] - R[j * 3];
            float dy = R[i * 3 + 1] - R[j * 3 + 1];
            float dz = R[i * 3 + 2] - R[j * 3 + 2];
            float v = QC / sqrtf(dx * dx + dy * dy + dz * dz);
            hv = f2bf(v);
            vr = bf2f(hv);
        }
        Af[(((m >> 4) * NCH + (tid >> 3)) * 16 + (m & 15)) * 8 + (tid & 7)] = hv;
        qxsG[(tid >> 2) * 256 + m * 4 + (tid & 3)] = vr;
        local = vr * vr;
    }
    red[tid] = local;
    __syncthreads();
    for (int s = 128; s > 0; s >>= 1) {
        if (tid < s) red[tid] += red[tid + s];
        __syncthreads();
    }
    if (tid == 0) nx[m] = red[0];
}

// Fused prep + stage-1. Grid 512: block b owns t-rows [b*16, b*16+16).
// Raw xs/Jx read ONCE -> single bf16 conversion into XOR-swizzled LDS image;
// from it: stage1 B-frags (ds_read_b128), stage2 B(T) frags to global,
// block-local rowstats. Es/Wa partials go straight to atomic accumulators.
__global__ __launch_bounds__(256) void k_s1p(
    const float* __restrict__ xs, const float* __restrict__ Jx,
    const unsigned short* __restrict__ Af, const float* __restrict__ nxg,
    unsigned short* __restrict__ XfT, unsigned short* __restrict__ JfT,
    unsigned short* __restrict__ w1f, unsigned short* __restrict__ e1f,
    float* __restrict__ EsA, float* __restrict__ WaA) {
    const int b = blockIdx.x, tid = threadIdx.x;
    const int lane = tid & 63;
    const int w = tid >> 6;                // mtile
    const int col = lane & 15, quad = lane >> 4;

    __shared__ unsigned short xJh[2 * 16 * DP];   // 14336 B, rows XOR-swizzled
    __shared__ float Dw[64][17];
    __shared__ float De[64][17];
    __shared__ float ntL[16], cjL[16];
    char* xB = (char*)xJh;

    // A-panel (L2-hot) + nx issued early, held through the prep phase
    const unsigned short* ap = Af + ((size_t)(w * NCH + quad) * 16 + col) * 8;
    bf8 af[7];
#pragma unroll
    for (int kc = 0; kc < 7; ++kc) af[kc] = *(const bf8*)(ap + kc * 512);
    float nxv[4];
#pragma unroll
    for (int r = 0; r < 4; ++r) nxv[r] = nxg[w * 16 + quad * 4 + r];

    // zero the d-pad [210,224): 2 arrays x 16 rows x 7 dwords
    if (tid < 224) {
        const int arr = tid / 112, rem = tid - arr * 112;
        const int t = rem / 7, k2 = rem - t * 7;
        *(unsigned*)(xB + arr * 7168 +
                     (((unsigned)(t * 448 + 420 + k2 * 4)) ^ ((unsigned)((t & 7) << 4)))) = 0u;
    }
    // load+convert: 1680 float2 per array; row = p/105 (210 even -> pairs never
    // cross rows); byte = t*448 + 2d = 4p + 28t, swizzled by ((t&7)<<4)
    const float2* sx = (const float2*)(xs + (size_t)b * 16 * ND);
    const float2* sj = (const float2*)(Jx + (size_t)b * 16 * ND);
#pragma unroll
    for (int k = 0; k < 7; ++k) {
        const int p = k * 256 + tid;
        if (p < 1680) {
            const float2 vx = sx[p];
            const float2 vj = sj[p];
            const int t = p / 105;
            const unsigned bo = ((unsigned)(4 * p + 28 * t)) ^ ((unsigned)((t & 7) << 4));
            *(unsigned*)(xB + bo) =
                (unsigned)f2bf(QC * vx.x) | ((unsigned)f2bf(QC * vx.y) << 16);
            *(unsigned*)(xB + 7168 + bo) =
                (unsigned)f2bf(vj.x) | ((unsigned)f2bf(vj.y) << 16);
        }
    }
    __syncthreads();

    // rowstats from the rounded bf16 image (pads are zero -> exact)
    {
        const int tt = tid >> 4, l = tid & 15;
        const unsigned swt = (unsigned)((tt & 7) << 4);
        float sn = 0.0f, sc2 = 0.0f;
#pragma unroll
        for (int c = l; c < DP; c += 16) {
            const unsigned off = ((unsigned)(tt * 448 + 2 * c)) ^ swt;
            const float x = bf2f(*(const unsigned short*)(xB + off));
            const float jv = bf2f(*(const unsigned short*)(xB + 7168 + off));
            sn = fmaf(x, x, sn);
            sc2 = fmaf(x, jv, sc2);
        }
#pragma unroll
        for (int o = 1; o < 16; o <<= 1) {
            sn += __shfl_xor(sn, o);
            sc2 += __shfl_xor(sc2, o);
        }
        if (l == 0) { ntL[tt] = sn; cjL[tt] = sc2; }
    }
    // stage2-B(T) frags to global (same values: pre-rounded bf16)
#pragma unroll
    for (int k = 0; k < 4; ++k) {
        const int idx = k * 256 + tid;
        if (idx < 896) {
            const int arr = idx / 448;
            const int rem = idx - arr * 448;
            const int dtile = rem >> 5;
            const int rem2 = rem & 31;
            const int tql = rem2 >> 4, cc = rem2 & 15;
            const int dbyte = 2 * (dtile * 16 + cc);
            union { unsigned short us[8]; uint4 v; } u;
#pragma unroll
            for (int i = 0; i < 8; ++i) {
                const int t = tql * 8 + i;
                const unsigned off =
                    ((unsigned)(t * 448 + dbyte)) ^ ((unsigned)((t & 7) << 4));
                u.us[i] = *(const unsigned short*)(xB + arr * 7168 + off);
            }
            const size_t o2 = ((size_t)(dtile * 1024 + b * 2 + tql) * 16 + cc) * 8;
            *(uint4*)((arr ? JfT : XfT) + o2) = u.v;
        }
    }
    __syncthreads();

    // stage-1 MFMA: A in regs, B straight from swizzled LDS (b128, conflict-free)
    const unsigned base0 = (unsigned)(col * 448 + quad * 16);
    const unsigned swc = (unsigned)((col & 7) << 4);
    bf8 bx[2], bj[2];
    bx[0] = *(const bf8*)(xB + (base0 ^ swc));
    bj[0] = *(const bf8*)(xB + 7168 + (base0 ^ swc));
    bx[1] = *(const bf8*)(xB + ((base0 + 64) ^ swc));
    bj[1] = *(const bf8*)(xB + 7168 + ((base0 + 64) ^ swc));
    f4 c1 = {0.f, 0.f, 0.f, 0.f};
    f4 c2 = {0.f, 0.f, 0.f, 0.f};
#pragma unroll
    for (int kc = 0; kc < 7; ++kc) {
        const int s = kc & 1;
        c1 = __builtin_amdgcn_mfma_f32_16x16x32_bf16(af[kc], bx[s], c1, 0, 0, 0);
        c2 = __builtin_amdgcn_mfma_f32_16x16x32_bf16(af[kc], bj[s], c2, 0, 0, 0);
        if (kc < 5) {
            bx[s] = *(const bf8*)(xB + ((base0 + (kc + 2) * 64) ^ swc));
            bj[s] = *(const bf8*)(xB + 7168 + ((base0 + (kc + 2) * 64) ^ swc));
        }
    }

    // epilogue: lane holds D[m=w*16+quad*4+r][t=b*16+col]
    const float ntv = ntL[col], cjv = cjL[col];
    float esA[4], wlA[4];
#pragma unroll
    for (int r = 0; r < 4; ++r) {
        const int m = w * 16 + quad * 4 + r;
        float sq = fmaxf(nxv[r] - 2.0f * c1[r] + ntv, 0.0f);
        float xd = sqrtf(sq);
        float e = KE * expf(-xd);
        float dotv = c2[r] - cjv;
        float wv = e * dotv;
        float ev = e * (1.0f + xd);
        Dw[m][col] = wv;
        De[m][col] = ev;
        esA[r] = ev * dotv;
        wlA[r] = wv;
    }
    __syncthreads();
    {   // coalesced frag-layout stores: 128 chunks per array
        const int aidx = tid >> 7;
        const int c = tid & 127;
        const int mtile = c >> 5, tql = (c >> 4) & 1, colm = c & 15;
        const float* srcD = aidx ? &De[0][0] : &Dw[0][0];
        unsigned short* dst = aidx ? e1f : w1f;
        const int m = mtile * 16 + colm;
        union { unsigned short us[8]; uint4 v; } u;
#pragma unroll
        for (int i = 0; i < 8; ++i) u.us[i] = f2bf(srcD[m * 17 + tql * 8 + i]);
        const size_t off = ((size_t)(mtile * 1024 + b * 2 + tql) * 16 + colm) * 8;
        *(uint4*)(dst + off) = u.v;
    }
#pragma unroll
    for (int r = 0; r < 4; ++r) {
        float e = esA[r], wl = wlA[r];
#pragma unroll
        for (int o = 1; o < 16; o <<= 1) {
            e += __shfl_xor(e, o);
            wl += __shfl_xor(wl, o);
        }
        if (col == 0) {
            const int m = w * 16 + quad * 4 + r;
            atomicAdd(&EsA[m], e);
            atomicAdd(&WaA[m], wl);
        }
    }
}

// Stage 2 (MFMA): grid (14 dtiles, 32 k-splits of 256 t). Wave w = mtile.
// All four frag streams contiguous coalesced, depth-2 prefetch. Output goes
// straight into the AB atomic accumulator (dA+dB summed — k_final only ever
// uses their sum), eliminating the Pbuf round trip.
__global__ __launch_bounds__(256) void k_stage2(
    const unsigned short* __restrict__ w1f, const unsigned short* __restrict__ e1f,
    const unsigned short* __restrict__ XfT, const unsigned short* __restrict__ JfT,
    float* __restrict__ AB) {
    const int tid = threadIdx.x;
    const int lane = tid & 63;
    const int w = tid >> 6;                // mtile
    const int col = lane & 15, quad = lane >> 4;
    const int dt = blockIdx.x;
    const int by = blockIdx.y;

    const unsigned short* awp = w1f + ((size_t)(w * 1024 + by * 32 + quad) * 16 + col) * 8;
    const unsigned short* aep = e1f + ((size_t)(w * 1024 + by * 32 + quad) * 16 + col) * 8;
    const unsigned short* bxp = XfT + ((size_t)(dt * 1024 + by * 32 + quad) * 16 + col) * 8;
    const unsigned short* bjp = JfT + ((size_t)(dt * 1024 + by * 32 + quad) * 16 + col) * 8;

    bf8 aw[2], ae[2], bx[2], bj[2];
    aw[0] = *(const bf8*)awp;         ae[0] = *(const bf8*)aep;
    bx[0] = *(const bf8*)bxp;         bj[0] = *(const bf8*)bjp;
    aw[1] = *(const bf8*)(awp + 512); ae[1] = *(const bf8*)(aep + 512);
    bx[1] = *(const bf8*)(bxp + 512); bj[1] = *(const bf8*)(bjp + 512);

    f4 dA = {0.f, 0.f, 0.f, 0.f};
    f4 dB = {0.f, 0.f, 0.f, 0.f};
#pragma unroll
    for (int kk = 0; kk < 8; ++kk) {
        const int s = kk & 1;
        dA = __builtin_amdgcn_mfma_f32_16x16x32_bf16(aw[s], bx[s], dA, 0, 0, 0);
        dB = __builtin_amdgcn_mfma_f32_16x16x32_bf16(ae[s], bj[s], dB, 0, 0, 0);
        if (kk < 6) {
            aw[s] = *(const bf8*)(awp + (kk + 2) * 512);
            ae[s] = *(const bf8*)(aep + (kk + 2) * 512);
            bx[s] = *(const bf8*)(bxp + (kk + 2) * 512);
            bj[s] = *(const bf8*)(bjp + (kk + 2) * 512);
        }
    }
    // lane holds D[m=w*16+quad*4+r][d=dt*16+col]; accumulate dA+dB
    float* p = AB + dt * 16 + col;
#pragma unroll
    for (int r = 0; r < 4; ++r) {
        const int m = w * 16 + quad * 4 + r;
        atomicAdd(p + (size_t)m * DP, dA[r] + dB[r]);
    }
}

// grid 64 (m) x 256: expand_tril + force contraction + Es. All inputs are
// tiny pre-reduced accumulators -> launch-bound stub.
__global__ void k_final(const float* __restrict__ Rs, const float* __restrict__ qxsG,
                        const float* __restrict__ AB, const float* __restrict__ EsA,
                        const float* __restrict__ WaA, float* __restrict__ out) {
    int m = blockIdx.x, tid = threadIdx.x;
    __shared__ float R[NA * 3];
    __shared__ float Ff[NA][NA];
    if (tid < NA * 3) R[tid] = Rs[m * NA * 3 + tid];
    if (tid < NA) Ff[tid][tid] = 0.0f;
    const float Wa = WaA[m];
    __syncthreads();
    if (tid < ND) {
        int i, j; d_to_ij(tid, i, j);
        float dx = R[i * 3] - R[j * 3];
        float dy = R[i * 3 + 1] - R[j * 3 + 1];
        float dz = R[i * 3 + 2] - R[j * 3 + 2];
        float dist2 = dx * dx + dy * dy + dz * dz;
        float fsx = qxsG[(tid >> 2) * 256 + m * 4 + (tid & 3)] * Wa - AB[m * DP + tid];
        float f = fsx / (dist2 * sqrtf(dist2));
        Ff[i][j] = f;
        Ff[j][i] = f;
    }
    __syncthreads();
    if (tid < NA * 3) {
        int a = tid / 3, c = tid % 3;
        float s = 0.0f;
        for (int b = 0; b < NA; ++b) {
            if (b == a) continue;
            s += Ff[a][b] * (R[a * 3 + c] - R[b * 3 + c]);
        }
        out[NM + m * NA * 3 + tid] = s;
    }
    if (tid == 0) out[m] = EsA[m] / QC;
}

extern "C" void kernel_launch(void* const* d_in, const int* in_sizes, int n_in,
                              void* d_out, int out_size, void* d_ws, size_t ws_size,
                              hipStream_t stream) {
    const float* Rs = (const float*)d_in[0];
    const float* xs_train = (const float*)d_in[1];
    const float* Jx_alphas = (const float*)d_in[2];
    float* out = (float*)d_out;
    float* ws = (float*)d_ws;

    unsigned short* XfT = (unsigned short*)(ws + O_XFT);
    unsigned short* JfT = (unsigned short*)(ws + O_JFT);
    unsigned short* w1f = (unsigned short*)(ws + O_W1);
    unsigned short* e1f = (unsigned short*)(ws + O_E1);
    unsigned short* Af  = (unsigned short*)(ws + O_AF);
    float* qxsG = ws + O_QG;
    float* nx   = ws + O_NX;
    float* AB   = ws + O_AB;
    float* EsA  = ws + O_ESA;
    float* WaA  = ws + O_WAA;

    k_geom<<<NM, 256, 0, stream>>>(Rs, Af, qxsG, nx, AB, EsA, WaA);
    k_s1p<<<512, 256, 0, stream>>>(xs_train, Jx_alphas, Af, nx, XfT, JfT,
                                   w1f, e1f, EsA, WaA);
    k_stage2<<<dim3(14, KS2), 256, 0, stream>>>(w1f, e1f, XfT, JfT, AB);
    k_final<<<NM, 256, 0, stream>>>(Rs, qxsG, AB, EsA, WaA, out);
}

// Round 4
// 85.265 us; speedup vs baseline: 1.5399x; 1.5399x over previous
//
#include <hip/hip_runtime.h>
#include <math.h>

#define NA   21
#define NM   64
#define ND   210
#define DP   224            // padded descriptor row
#define NT   8192
#define NCH  28             // 8-wide k-chunks per descriptor row (224/8)
#define KS2  32             // stage2 K-splits (256 t each)

#define QC 0.22360679774997896f   // sqrt(5)/10
#define KE 0.016666666666666666f  // 5/(3*sig^2)

typedef short bf8 __attribute__((ext_vector_type(8)));   // 8 bf16 (4 VGPRs)
typedef float f4  __attribute__((ext_vector_type(4)));   // 4 fp32 acc

// ---- workspace layout (float offsets); bf16 arrays count elems/2 ----
// XfT/JfT: stage2 B frags [dtile 14][tq 1024][col_d 16][8 t]
// w1f/e1f: stage2 A frags [mtile 4][tq 1024][col_m 16][8 t]
// Af     : stage1 A frags [mtile 4][kq 28][col_m 16][8 d]
// Pbuf   : [m 64][ks 32][d 224] fp32 (dA+dB pre-summed)
// EsPart/WaPart: [m 64][ttile 512] fp32
#define O_XFT  1835008u
#define O_JFT  2752512u
#define O_W1   3670016u
#define O_E1   3932160u
#define O_AF   4194304u
#define O_QG   4201472u        // qxsG fp32 [56][64][4]
#define O_NX   4232192u        // [64]
#define O_PB   4261056u        // 458752 floats
#define O_ESP  5178560u        // [64][512]
#define O_WAP  5211328u        // [64][512]

__device__ __forceinline__ unsigned short f2bf(float f) {
    unsigned u = __float_as_uint(f);
    u += 0x7fffu + ((u >> 16) & 1u);
    return (unsigned short)(u >> 16);
}
__device__ __forceinline__ float bf2f(unsigned short h) {
    return __uint_as_float((unsigned)h << 16);
}

__device__ __forceinline__ void d_to_ij(int d, int& i, int& j) {
    int ii = (int)((1.0f + sqrtf(1.0f + 8.0f * (float)d)) * 0.5f);
    while (ii * (ii - 1) / 2 > d) --ii;
    while ((ii + 1) * ii / 2 <= d) ++ii;
    i = ii;
    j = d - ii * (ii - 1) / 2;
}

// Tiny geometry prep: per-molecule descriptors -> Af frags, qxsG, nx.
__global__ __launch_bounds__(256) void k_geom(
    const float* __restrict__ Rs, unsigned short* __restrict__ Af,
    float* __restrict__ qxsG, float* __restrict__ nx) {
    const int m = blockIdx.x, tid = threadIdx.x;
    __shared__ float R[NA * 3];
    __shared__ float red[256];
    if (tid < NA * 3) R[tid] = Rs[m * NA * 3 + tid];
    __syncthreads();
    float local = 0.0f;
    if (tid < DP) {
        float vr = 0.0f;
        unsigned short hv = 0;
        if (tid < ND) {
            int i, j; d_to_ij(tid, i, j);
            float dx = R[i * 3] - R[j * 3];
            float dy = R[i * 3 + 1] - R[j * 3 + 1];
            float dz = R[i * 3 + 2] - R[j * 3 + 2];
            float v = QC / sqrtf(dx * dx + dy * dy + dz * dz);
            hv = f2bf(v);
            vr = bf2f(hv);
        }
        Af[(((m >> 4) * NCH + (tid >> 3)) * 16 + (m & 15)) * 8 + (tid & 7)] = hv;
        qxsG[(tid >> 2) * 256 + m * 4 + (tid & 3)] = vr;
        local = vr * vr;
    }
    red[tid] = local;
    __syncthreads();
    for (int s = 128; s > 0; s >>= 1) {
        if (tid < s) red[tid] += red[tid + s];
        __syncthreads();
    }
    if (tid == 0) nx[m] = red[0];
}

// Fused prep + stage-1. Grid 512: block b owns t-rows [b*16, b*16+16).
// Phase order tuned for latency: image -> MFMA issued FIRST, rowstats runs in
// the MFMA shadow; the 896-chunk XfT/JfT writeout and all stores happen last.
__global__ __launch_bounds__(256) void k_s1p(
    const float* __restrict__ xs, const float* __restrict__ Jx,
    const unsigned short* __restrict__ Af, const float* __restrict__ nxg,
    unsigned short* __restrict__ XfT, unsigned short* __restrict__ JfT,
    unsigned short* __restrict__ w1f, unsigned short* __restrict__ e1f,
    float* __restrict__ EsPart, float* __restrict__ WaPart) {
    const int b = blockIdx.x, tid = threadIdx.x;
    const int lane = tid & 63;
    const int w = tid >> 6;                // mtile
    const int col = lane & 15, quad = lane >> 4;

    __shared__ unsigned short xJh[2 * 16 * DP];   // 14336 B, rows XOR-swizzled
    __shared__ float Dw[64][17];
    __shared__ float De[64][17];
    __shared__ float ntL[16], cjL[16];
    char* xB = (char*)xJh;

    // A-panel (L2-hot) + nx issued early, held through the prep phase
    const unsigned short* ap = Af + ((size_t)(w * NCH + quad) * 16 + col) * 8;
    bf8 af[7];
#pragma unroll
    for (int kc = 0; kc < 7; ++kc) af[kc] = *(const bf8*)(ap + kc * 512);
    float nxv[4];
#pragma unroll
    for (int r = 0; r < 4; ++r) nxv[r] = nxg[w * 16 + quad * 4 + r];

    // zero the d-pad [210,224): 2 arrays x 16 rows x 7 dwords
    if (tid < 224) {
        const int arr = tid / 112, rem = tid - arr * 112;
        const int t = rem / 7, k2 = rem - t * 7;
        *(unsigned*)(xB + arr * 7168 +
                     (((unsigned)(t * 448 + 420 + k2 * 4)) ^ ((unsigned)((t & 7) << 4)))) = 0u;
    }
    // load+convert: 1680 float2 per array; row = p/105 (210 even -> pairs never
    // cross rows); byte = t*448 + 2d = 4p + 28t, swizzled by ((t&7)<<4)
    const float2* sx = (const float2*)(xs + (size_t)b * 16 * ND);
    const float2* sj = (const float2*)(Jx + (size_t)b * 16 * ND);
#pragma unroll
    for (int k = 0; k < 7; ++k) {
        const int p = k * 256 + tid;
        if (p < 1680) {
            const float2 vx = sx[p];
            const float2 vj = sj[p];
            const int t = p / 105;
            const unsigned bo = ((unsigned)(4 * p + 28 * t)) ^ ((unsigned)((t & 7) << 4));
            *(unsigned*)(xB + bo) =
                (unsigned)f2bf(QC * vx.x) | ((unsigned)f2bf(QC * vx.y) << 16);
            *(unsigned*)(xB + 7168 + bo) =
                (unsigned)f2bf(vj.x) | ((unsigned)f2bf(vj.y) << 16);
        }
    }
    __syncthreads();

    // ---- MFMA first: A in regs, B straight from swizzled LDS (conflict-free)
    const unsigned base0 = (unsigned)(col * 448 + quad * 16);
    const unsigned swc = (unsigned)((col & 7) << 4);
    bf8 bx[2], bj[2];
    bx[0] = *(const bf8*)(xB + (base0 ^ swc));
    bj[0] = *(const bf8*)(xB + 7168 + (base0 ^ swc));
    bx[1] = *(const bf8*)(xB + ((base0 + 64) ^ swc));
    bj[1] = *(const bf8*)(xB + 7168 + ((base0 + 64) ^ swc));
    f4 c1 = {0.f, 0.f, 0.f, 0.f};
    f4 c2 = {0.f, 0.f, 0.f, 0.f};
#pragma unroll
    for (int kc = 0; kc < 7; ++kc) {
        const int s = kc & 1;
        c1 = __builtin_amdgcn_mfma_f32_16x16x32_bf16(af[kc], bx[s], c1, 0, 0, 0);
        c2 = __builtin_amdgcn_mfma_f32_16x16x32_bf16(af[kc], bj[s], c2, 0, 0, 0);
        if (kc < 5) {
            bx[s] = *(const bf8*)(xB + ((base0 + (kc + 2) * 64) ^ swc));
            bj[s] = *(const bf8*)(xB + 7168 + ((base0 + (kc + 2) * 64) ^ swc));
        }
    }

    // ---- rowstats in the MFMA shadow (pads are zero -> exact)
    {
        const int tt = tid >> 4, l = tid & 15;
        const unsigned swt = (unsigned)((tt & 7) << 4);
        float sn = 0.0f, sc2 = 0.0f;
#pragma unroll
        for (int c = l; c < DP; c += 16) {
            const unsigned off = ((unsigned)(tt * 448 + 2 * c)) ^ swt;
            const float x = bf2f(*(const unsigned short*)(xB + off));
            const float jv = bf2f(*(const unsigned short*)(xB + 7168 + off));
            sn = fmaf(x, x, sn);
            sc2 = fmaf(x, jv, sc2);
        }
#pragma unroll
        for (int o = 1; o < 16; o <<= 1) {
            sn += __shfl_xor(sn, o);
            sc2 += __shfl_xor(sc2, o);
        }
        if (l == 0) { ntL[tt] = sn; cjL[tt] = sc2; }
    }
    __syncthreads();

    // ---- epilogue: lane holds D[m=w*16+quad*4+r][t=b*16+col]
    const float ntv = ntL[col], cjv = cjL[col];
    float esA[4], wlA[4];
#pragma unroll
    for (int r = 0; r < 4; ++r) {
        const int m = w * 16 + quad * 4 + r;
        float sq = fmaxf(nxv[r] - 2.0f * c1[r] + ntv, 0.0f);
        float xd = sqrtf(sq);
        float e = KE * expf(-xd);
        float dotv = c2[r] - cjv;
        float wv = e * dotv;
        float ev = e * (1.0f + xd);
        Dw[m][col] = wv;
        De[m][col] = ev;
        esA[r] = ev * dotv;
        wlA[r] = wv;
    }
    __syncthreads();

    // ---- all stores last (overlap each other; nothing downstream in-kernel)
    {   // coalesced frag-layout stores: 128 chunks per array
        const int aidx = tid >> 7;
        const int c = tid & 127;
        const int mtile = c >> 5, tql = (c >> 4) & 1, colm = c & 15;
        const float* srcD = aidx ? &De[0][0] : &Dw[0][0];
        unsigned short* dst = aidx ? e1f : w1f;
        const int m = mtile * 16 + colm;
        union { unsigned short us[8]; uint4 v; } u;
#pragma unroll
        for (int i = 0; i < 8; ++i) u.us[i] = f2bf(srcD[m * 17 + tql * 8 + i]);
        const size_t off = ((size_t)(mtile * 1024 + b * 2 + tql) * 16 + colm) * 8;
        *(uint4*)(dst + off) = u.v;
    }
    // stage2-B(T) frags to global (reads xJh, untouched since phase 1)
#pragma unroll
    for (int k = 0; k < 4; ++k) {
        const int idx = k * 256 + tid;
        if (idx < 896) {
            const int arr = idx / 448;
            const int rem = idx - arr * 448;
            const int dtile = rem >> 5;
            const int rem2 = rem & 31;
            const int tql = rem2 >> 4, cc = rem2 & 15;
            const int dbyte = 2 * (dtile * 16 + cc);
            union { unsigned short us[8]; uint4 v; } u;
#pragma unroll
            for (int i = 0; i < 8; ++i) {
                const int t = tql * 8 + i;
                const unsigned off =
                    ((unsigned)(t * 448 + dbyte)) ^ ((unsigned)((t & 7) << 4));
                u.us[i] = *(const unsigned short*)(xB + arr * 7168 + off);
            }
            const size_t o2 = ((size_t)(dtile * 1024 + b * 2 + tql) * 16 + cc) * 8;
            *(uint4*)((arr ? JfT : XfT) + o2) = u.v;
        }
    }
#pragma unroll
    for (int r = 0; r < 4; ++r) {
        float e = esA[r], wl = wlA[r];
#pragma unroll
        for (int o = 1; o < 16; o <<= 1) {
            e += __shfl_xor(e, o);
            wl += __shfl_xor(wl, o);
        }
        if (col == 0) {
            const int m = w * 16 + quad * 4 + r;
            EsPart[(size_t)m * 512 + b] = e;
            WaPart[(size_t)m * 512 + b] = wl;
        }
    }
}

// Stage 2 (MFMA): grid (14 dtiles, 32 k-splits of 256 t). Wave w = mtile.
// All four frag streams contiguous coalesced, depth-2 prefetch.
// Output: Pbuf[m][ks][d] = dA+dB (pre-summed; k_final only uses the sum).
// Each 64-B line of Pbuf is written entirely by one wave-quad of one block.
__global__ __launch_bounds__(256) void k_stage2(
    const unsigned short* __restrict__ w1f, const unsigned short* __restrict__ e1f,
    const unsigned short* __restrict__ XfT, const unsigned short* __restrict__ JfT,
    float* __restrict__ Pbuf) {
    const int tid = threadIdx.x;
    const int lane = tid & 63;
    const int w = tid >> 6;                // mtile
    const int col = lane & 15, quad = lane >> 4;
    const int dt = blockIdx.x;
    const int by = blockIdx.y;

    const unsigned short* awp = w1f + ((size_t)(w * 1024 + by * 32 + quad) * 16 + col) * 8;
    const unsigned short* aep = e1f + ((size_t)(w * 1024 + by * 32 + quad) * 16 + col) * 8;
    const unsigned short* bxp = XfT + ((size_t)(dt * 1024 + by * 32 + quad) * 16 + col) * 8;
    const unsigned short* bjp = JfT + ((size_t)(dt * 1024 + by * 32 + quad) * 16 + col) * 8;

    bf8 aw[2], ae[2], bx[2], bj[2];
    aw[0] = *(const bf8*)awp;         ae[0] = *(const bf8*)aep;
    bx[0] = *(const bf8*)bxp;         bj[0] = *(const bf8*)bjp;
    aw[1] = *(const bf8*)(awp + 512); ae[1] = *(const bf8*)(aep + 512);
    bx[1] = *(const bf8*)(bxp + 512); bj[1] = *(const bf8*)(bjp + 512);

    f4 dA = {0.f, 0.f, 0.f, 0.f};
    f4 dB = {0.f, 0.f, 0.f, 0.f};
#pragma unroll
    for (int kk = 0; kk < 8; ++kk) {
        const int s = kk & 1;
        dA = __builtin_amdgcn_mfma_f32_16x16x32_bf16(aw[s], bx[s], dA, 0, 0, 0);
        dB = __builtin_amdgcn_mfma_f32_16x16x32_bf16(ae[s], bj[s], dB, 0, 0, 0);
        if (kk < 6) {
            aw[s] = *(const bf8*)(awp + (kk + 2) * 512);
            ae[s] = *(const bf8*)(aep + (kk + 2) * 512);
            bx[s] = *(const bf8*)(bxp + (kk + 2) * 512);
            bj[s] = *(const bf8*)(bjp + (kk + 2) * 512);
        }
    }
    // lane holds D[m=w*16+quad*4+r][d=dt*16+col]
#pragma unroll
    for (int r = 0; r < 4; ++r) {
        const int m = w * 16 + quad * 4 + r;
        Pbuf[((size_t)(m * KS2 + by)) * DP + dt * 16 + col] = dA[r] + dB[r];
    }
}

// grid 64 (m) x 256: fused Pbuf ks-reduction (warp-coalesced per ks-slice) +
// Es/Wa partial reduce + expand_tril + force contraction + Es
__global__ void k_final(const float* __restrict__ Rs, const float* __restrict__ qxsG,
                        const float* __restrict__ Pbuf, const float* __restrict__ EsPart,
                        const float* __restrict__ WaPart, float* __restrict__ out) {
    int m = blockIdx.x, tid = threadIdx.x;
    __shared__ float R[NA * 3];
    __shared__ float Ff[NA][NA];
    __shared__ float redE[256];
    __shared__ float redW[256];
    __shared__ float ABs[DP];
    if (tid < NA * 3) R[tid] = Rs[m * NA * 3 + tid];
    if (tid < NA) Ff[tid][tid] = 0.0f;
    if (tid < DP) {   // ks-reduction: 32 independent loads, coalesced per slice
        const float* p0 = Pbuf + (size_t)m * KS2 * DP + tid;
        float s1 = 0.0f;
#pragma unroll
        for (int ks = 0; ks < KS2; ++ks) s1 += p0[ks * DP];
        ABs[tid] = s1;
    }
    {   // contiguous per-m Es/Wa partials
        const float2 ep = ((const float2*)(EsPart + (size_t)m * 512))[tid];
        const float2 wp = ((const float2*)(WaPart + (size_t)m * 512))[tid];
        redE[tid] = ep.x + ep.y;
        redW[tid] = wp.x + wp.y;
    }
    __syncthreads();
    for (int s = 128; s > 0; s >>= 1) {
        if (tid < s) {
            redE[tid] += redE[tid + s];
            redW[tid] += redW[tid + s];
        }
        __syncthreads();
    }
    const float Wa = redW[0];
    if (tid < ND) {
        int i, j; d_to_ij(tid, i, j);
        float dx = R[i * 3] - R[j * 3];
        float dy = R[i * 3 + 1] - R[j * 3 + 1];
        float dz = R[i * 3 + 2] - R[j * 3 + 2];
        float dist2 = dx * dx + dy * dy + dz * dz;
        float fsx = qxsG[(tid >> 2) * 256 + m * 4 + (tid & 3)] * Wa - ABs[tid];
        float f = fsx / (dist2 * sqrtf(dist2));
        Ff[i][j] = f;
        Ff[j][i] = f;
    }
    __syncthreads();
    if (tid < NA * 3) {
        int a = tid / 3, c = tid % 3;
        float s = 0.0f;
        for (int b = 0; b < NA; ++b) {
            if (b == a) continue;
            s += Ff[a][b] * (R[a * 3 + c] - R[b * 3 + c]);
        }
        out[NM + m * NA * 3 + tid] = s;
    }
    if (tid == 0) out[m] = redE[0] / QC;
}

extern "C" void kernel_launch(void* const* d_in, const int* in_sizes, int n_in,
                              void* d_out, int out_size, void* d_ws, size_t ws_size,
                              hipStream_t stream) {
    const float* Rs = (const float*)d_in[0];
    const float* xs_train = (const float*)d_in[1];
    const float* Jx_alphas = (const float*)d_in[2];
    float* out = (float*)d_out;
    float* ws = (float*)d_ws;

    unsigned short* XfT = (unsigned short*)(ws + O_XFT);
    unsigned short* JfT = (unsigned short*)(ws + O_JFT);
    unsigned short* w1f = (unsigned short*)(ws + O_W1);
    unsigned short* e1f = (unsigned short*)(ws + O_E1);
    unsigned short* Af  = (unsigned short*)(ws + O_AF);
    float* qxsG   = ws + O_QG;
    float* nx     = ws + O_NX;
    float* Pbuf   = ws + O_PB;
    float* EsPart = ws + O_ESP;
    float* WaPart = ws + O_WAP;

    k_geom<<<NM, 256, 0, stream>>>(Rs, Af, qxsG, nx);
    k_s1p<<<512, 256, 0, stream>>>(xs_train, Jx_alphas, Af, nx, XfT, JfT,
                                   w1f, e1f, EsPart, WaPart);
    k_stage2<<<dim3(14, KS2), 256, 0, stream>>>(w1f, e1f, XfT, JfT, Pbuf);
    k_final<<<NM, 256, 0, stream>>>(Rs, qxsG, Pbuf, EsPart, WaPart, out);
}